// Round 9
// baseline (1188.385 us; speedup 1.0000x reference)
//
#include <hip/hip_runtime.h>
#include <cstddef>
#include <cstdint>

#define N_NODES 5120
#define E_EDGES 163840
#define F 256
#define TSTEPS 24
#define ND 1024          // GEMM N = 4*256 (gates, column-permuted)
#define XROWSTRIDE 6144  // T*F

typedef unsigned short u16;
typedef unsigned int u32;
typedef __bf16 bf16x8 __attribute__((ext_vector_type(8)));
typedef float f32x4 __attribute__((ext_vector_type(4)));

__device__ __forceinline__ u16 f2bf(float f) {
    u32 u = __float_as_uint(f);
    u = (u + 0x7FFFu + ((u >> 16) & 1u)) >> 16;  // round-to-nearest-even
    return (u16)u;
}
__device__ __forceinline__ float bf2f(u16 h) {
    return __uint_as_float((u32)h << 16);
}
__device__ __forceinline__ float fsigmoid(float x) {
    return 1.f / (1.f + __expf(-x));
}
__device__ __forceinline__ float ftanh(float x) {
    // tanh(x) = 1 - 2/(exp(2x)+1); saturates correctly for |x| large
    return 1.f - 2.f / (__expf(2.f * x) + 1.f);
}

// ---------------- graph preprocessing ----------------

__global__ void deg_kernel(const float* __restrict__ ew, const int* __restrict__ src,
                           float* __restrict__ deg) {
    int e = blockIdx.x * 256 + threadIdx.x;
    if (e < E_EDGES) atomicAdd(&deg[src[e]], ew[e]);
}

__global__ void dis_kernel(float* __restrict__ deg) {
    int n = blockIdx.x * 256 + threadIdx.x;
    if (n < N_NODES) {
        float d = deg[n];
        deg[n] = d > 0.f ? rsqrtf(d) : 0.f;
    }
}

__global__ void count_kernel(const int* __restrict__ dst, int* __restrict__ cnt) {
    int e = blockIdx.x * 256 + threadIdx.x;
    if (e < E_EDGES) atomicAdd(&cnt[dst[e]], 1);
}

// one block, 256 threads, 20 counts each (N_NODES = 256*20)
__global__ void scan_kernel(const int* __restrict__ cnt, int* __restrict__ row_ptr) {
    __shared__ int s[256];
    int tid = threadIdx.x;
    int base = tid * 20;
    int local[20];
    int sum = 0;
    #pragma unroll
    for (int i = 0; i < 20; i++) { local[i] = sum; sum += cnt[base + i]; }
    s[tid] = sum;
    __syncthreads();
    for (int off = 1; off < 256; off <<= 1) {
        int v = (tid >= off) ? s[tid - off] : 0;
        __syncthreads();
        s[tid] += v;
        __syncthreads();
    }
    int offset = (tid == 0) ? 0 : s[tid - 1];
    #pragma unroll
    for (int i = 0; i < 20; i++) row_ptr[base + i] = offset + local[i];
    if (tid == 0) row_ptr[N_NODES] = E_EDGES;
}

__global__ void fill_csr(const int* __restrict__ src, const int* __restrict__ dst,
                         const float* __restrict__ ew, const float* __restrict__ dis,
                         const int* __restrict__ row_ptr, int* __restrict__ cursor,
                         int* __restrict__ csr_src, float* __restrict__ csr_w) {
    int e = blockIdx.x * 256 + threadIdx.x;
    if (e >= E_EDGES) return;
    int s = src[e], d = dst[e];
    int pos = row_ptr[d] + atomicAdd(&cursor[d], 1);
    csr_src[pos] = s;
    // w_hat = (2/lambda_max)*(-dis[src]*w*dis[dst]); lambda_max=2 -> factor 1
    csr_w[pos] = -dis[s] * ew[e] * dis[d];
}

// Column permutation (8-feature gate interleave so a 32-col wave slice holds
// all 4 gates): col'(g, j) = (j>>3)*32 + g*8 + (j&7).
// Inverse: g = (c>>3)&3, j = (c>>5)*8 + (c&7).
// WT[c'][k] (bf16, k contiguous) = Wcat[k][g*256+j]
__global__ void build_wcatT(const float* __restrict__ Ws, const float* __restrict__ thetas,
                            u16* __restrict__ WT) {
    int idx = blockIdx.x * 256 + threadIdx.x;
    if (idx >= 1024 * 1024) return;
    int c = idx >> 10, k = idx & 1023;
    int g = (c >> 3) & 3;
    int j = (c >> 5) * 8 + (c & 7);
    float v;
    if (k < 256) {
        v = Ws[(g * 256 + k) * 256 + j];
    } else {
        int kc = (k >> 8) - 1;  // 0..2
        int rr = k & 255;
        v = thetas[((g * 3 + kc) * 256 + rr) * 256 + j];
    }
    WT[idx] = f2bf(v);
}

// bsum[c'] = bs[g*256+j] + cbs[g*256+j] in permuted column order
__global__ void build_bsum(const float* __restrict__ bs, const float* __restrict__ cbs,
                           float* __restrict__ bsum) {
    int c = blockIdx.x * 256 + threadIdx.x;
    if (c >= 1024) return;
    int g = (c >> 3) & 3;
    int j = (c >> 5) * 8 + (c & 7);
    bsum[c] = bs[g * 256 + j] + cbs[g * 256 + j];
}

// ---------------- prop: wave-per-node edge gather ----------------

__global__ __launch_bounds__(256) void prop_kernel(
        const u16* __restrict__ xin, const u16* __restrict__ sub, float scale,
        const int* __restrict__ row_ptr, const int* __restrict__ csr_src,
        const float* __restrict__ csr_w, u16* __restrict__ out_bf,
        const float* __restrict__ X, int t, u16* __restrict__ xt_out) {
    __shared__ int s_src[4][64];
    __shared__ float s_w[4][64];
    int wid = threadIdx.x >> 6, l = threadIdx.x & 63;
    int n = blockIdx.x * 4 + wid;
    int start = row_ptr[n], end = row_ptr[n + 1];
    float acc0 = 0.f, acc1 = 0.f, acc2 = 0.f, acc3 = 0.f;
    int fb = l * 4;  // this lane's 4 features
    for (int base = start; base < end; base += 64) {
        int chunk = min(64, end - base);
        if (l < chunk) {
            s_src[wid][l] = csr_src[base + l];
            s_w[wid][l] = csr_w[base + l];
        }
        #pragma unroll 4
        for (int i = 0; i < chunk; i++) {
            int s = s_src[wid][i];
            float wt = s_w[wid][i];
            ushort4 hv = *(const ushort4*)(xin + (size_t)s * F + fb);
            acc0 += wt * bf2f(hv.x);
            acc1 += wt * bf2f(hv.y);
            acc2 += wt * bf2f(hv.z);
            acc3 += wt * bf2f(hv.w);
        }
    }
    size_t o = (size_t)n * F + fb;
    float r0 = scale * acc0, r1 = scale * acc1, r2 = scale * acc2, r3 = scale * acc3;
    if (sub) {
        ushort4 sv = *(const ushort4*)(sub + o);
        r0 -= bf2f(sv.x); r1 -= bf2f(sv.y); r2 -= bf2f(sv.z); r3 -= bf2f(sv.w);
    }
    ushort4 ov;
    ov.x = f2bf(r0); ov.y = f2bf(r1); ov.z = f2bf(r2); ov.w = f2bf(r3);
    *(ushort4*)(out_bf + o) = ov;
    if (xt_out) {
        float4 xv = *(const float4*)(X + (size_t)n * XROWSTRIDE + (size_t)t * F + fb);
        ushort4 xo;
        xo.x = f2bf(xv.x); xo.y = f2bf(xv.y); xo.z = f2bf(xv.z); xo.w = f2bf(xv.w);
        *(ushort4*)(xt_out + o) = xo;
    }
}

// ---------------- fused bf16 MFMA GEMM + LSTM epilogue ----------------
// Tile 80x128 -> grid 64x8 = 512 blocks = EXACTLY 2.0 blocks/CU (no tail).
// 4 waves; each wave owns ALL 80 rows x a 32-col slice (acc[5][2]).
// K-loop = R4-proven single-buffered: stage -> sync -> compute -> sync.
// Epilogue: 32-col slice holds [I8|F8|T8|O8]; shfl_xor(8) partner exchange
// gives each lane all 4 gates; lanes cc<8 do regs{0,1}, cc>=8 regs{2,3}.
// A[5120,1024] = [Xt | Hb | Tx1 | Tx2] (bf16, row stride 256)
// WT = B^T in permuted column order (n-major, k-contig)
#define GBM 80
#define GBN 128
#define GBK 64

__global__ __launch_bounds__(256) void mfma_gemm(
        const u16* __restrict__ Xt, const u16* __restrict__ Hb,
        const u16* __restrict__ T1, const u16* __restrict__ T2,
        const u16* __restrict__ WT, const float* __restrict__ bsum,
        float* __restrict__ Cst, float* __restrict__ Hout, u16* __restrict__ HbNew,
        int writeH, int isFirst) {
    __shared__ alignas(16) u16 As[GBM * GBK];
    __shared__ alignas(16) u16 Bs[GBN * GBK];
    int tid = threadIdx.x;
    int w = tid >> 6, l = tid & 63;
    int m0 = blockIdx.x * GBM, n0 = blockIdx.y * GBN;
    int wn = w * 32;   // wave col slice

    // staging: chunk c covers LDS rows [c*8, c*8+8); lane l -> row c*8 + l/8.
    // rule #21: linear LDS dest + inverse-swizzled SOURCE col + swizzled READ.
    int srow = l >> 3;                // row & 7
    int scol = 8 * ((l & 7) ^ srow);  // source elem col for this lane's 16B

    // A: 80 rows = 10 chunks; waves 0,1 take 3 chunks, waves 2,3 take 2.
    int nA = (w < 2) ? 3 : 2;
    int cA0 = (w < 2) ? w * 3 : 6 + (w - 2) * 2;

    f32x4 acc[5][2] = {};

    for (int k0 = 0; k0 < 1024; k0 += GBK) {
        int seg = k0 >> 8;
        const u16* ab = (seg == 0) ? Xt : (seg == 1) ? Hb : (seg == 2) ? T1 : T2;
        ab += (k0 & 255);
        const u16* bb = WT + k0;
        for (int i = 0; i < nA; i++) {
            int c = cA0 + i;
            int row = c * 8 + srow;
            __builtin_amdgcn_global_load_lds(
                (const __attribute__((address_space(1))) u32*)(ab + (size_t)(m0 + row) * F + scol),
                (__attribute__((address_space(3))) u32*)(As + c * 512), 16, 0, 0);
        }
        // B: 128 rows = 16 chunks (4 per wave)
        #pragma unroll
        for (int i = 0; i < 4; i++) {
            int c = i * 4 + w;
            int row = c * 8 + srow;
            __builtin_amdgcn_global_load_lds(
                (const __attribute__((address_space(1))) u32*)(bb + (size_t)(n0 + row) * 1024 + scol),
                (__attribute__((address_space(3))) u32*)(Bs + c * 512), 16, 0, 0);
        }
        __syncthreads();
        #pragma unroll
        for (int kk = 0; kk < 2; kk++) {
            int kr = kk * 32 + (l >> 4) * 8;
            bf16x8 af[5], bfr[2];
            #pragma unroll
            for (int mf = 0; mf < 5; mf++) {
                int r = mf * 16 + (l & 15);
                af[mf] = *(const bf16x8*)(As + r * GBK + (kr ^ ((r & 7) << 3)));
            }
            #pragma unroll
            for (int nf = 0; nf < 2; nf++) {
                int r = wn + nf * 16 + (l & 15);
                bfr[nf] = *(const bf16x8*)(Bs + r * GBK + (kr ^ ((r & 7) << 3)));
            }
            #pragma unroll
            for (int mf = 0; mf < 5; mf++)
                #pragma unroll
                for (int nf = 0; nf < 2; nf++)
                    acc[mf][nf] = __builtin_amdgcn_mfma_f32_16x16x32_bf16(
                        af[mf], bfr[nf], acc[mf][nf], 0, 0, 0);
        }
        __syncthreads();
    }

    // LSTM epilogue. C/D layout: col = lane&15, row = (lane>>4)*4 + reg.
    // Wave cols nb..nb+31 = [I 8f | F 8f | T 8f | O 8f]; frag0 = I/F, frag1 = T/O.
    int cr = (l >> 4) * 4, cc = l & 15;
    int half = cc >> 3, f8 = cc & 7;
    int nb = n0 + wn;
    int feat = (nb >> 5) * 8 + f8;
    float bI = bsum[nb + f8];
    float bF = bsum[nb + 8 + f8];
    float bT = bsum[nb + 16 + f8];
    float bO = bsum[nb + 24 + f8];
    #pragma unroll
    for (int mf = 0; mf < 5; mf++) {
        float own0[4], own1[4], rec0[4], rec1[4];
        #pragma unroll
        for (int rg = 0; rg < 4; rg++) {
            own0[rg] = acc[mf][0][rg];
            own1[rg] = acc[mf][1][rg];
            rec0[rg] = __shfl_xor(own0[rg], 8, 64);
            rec1[rg] = __shfl_xor(own1[rg], 8, 64);
        }
        #pragma unroll
        for (int q = 0; q < 2; q++) {
            int rg = half * 2 + q;     // lanes cc<8: regs 0,1; cc>=8: regs 2,3
            float vI = half ? rec0[rg] : own0[rg];
            float vF = half ? own0[rg] : rec0[rg];
            float vT = half ? rec1[rg] : own1[rg];
            float vO = half ? own1[rg] : rec1[rg];
            int row = m0 + mf * 16 + cr + rg;
            size_t o = (size_t)row * F + feat;
            float I  = fsigmoid(vI + bI);
            float Fg = fsigmoid(vF + bF);
            float Tc = ftanh(vT + bT);
            float O  = fsigmoid(vO + bO);
            float cprev = isFirst ? 0.f : Cst[o];   // t=0: C starts at zero (buffer poisoned)
            float c  = Fg * cprev + I * Tc;
            Cst[o] = c;
            float h = O * ftanh(c);
            if (writeH) Hout[o] = h;   // fp32 H only needed at the final step
            HbNew[o] = f2bf(h);
        }
    }
}

// ---------------- launch ----------------

extern "C" void kernel_launch(void* const* d_in, const int* in_sizes, int n_in,
                              void* d_out, int out_size, void* d_ws, size_t ws_size,
                              hipStream_t stream) {
    const float* X   = (const float*)d_in[0];
    const float* ew  = (const float*)d_in[1];
    const float* Ws  = (const float*)d_in[2];
    const float* bs  = (const float*)d_in[3];
    const float* th  = (const float*)d_in[4];
    const float* cbs = (const float*)d_in[5];
    const int*   ei  = (const int*)d_in[6];
    const int* src = ei;
    const int* dst = ei + E_EDGES;

    float* H = (float*)d_out;               // N*F
    float* C = H + (size_t)N_NODES * F;     // N*F

    char* w = (char*)d_ws;
    size_t off = 0;
    auto alloc = [&](size_t bytes) {
        void* p = w + off;
        off += (bytes + 255) & ~(size_t)255;
        return p;
    };
    float* deg     = (float*)alloc(N_NODES * 4);
    int*   cnt     = (int*)  alloc(N_NODES * 4);
    int*   cursor  = (int*)  alloc(N_NODES * 4);
    int*   row_ptr = (int*)  alloc((N_NODES + 1) * 4);
    int*   csr_src = (int*)  alloc(E_EDGES * 4);
    float* csr_w   = (float*)alloc(E_EDGES * 4);
    u16*   WT      = (u16*)  alloc((size_t)1024 * 1024 * 2);
    float* bsum    = (float*)alloc(1024 * 4);
    u16*   Xtbf    = (u16*)  alloc((size_t)N_NODES * F * 2);
    u16*   Hb0     = (u16*)  alloc((size_t)N_NODES * F * 2);
    u16*   Hb1     = (u16*)  alloc((size_t)N_NODES * F * 2);
    u16*   Tx1bf   = (u16*)  alloc((size_t)N_NODES * F * 2);
    u16*   Tx2bf   = (u16*)  alloc((size_t)N_NODES * F * 2);

    hipMemsetAsync(Hb0, 0, (size_t)N_NODES * F * 2, stream);
    hipMemsetAsync(deg, 0, N_NODES * 4, stream);
    hipMemsetAsync(cnt, 0, N_NODES * 4, stream);
    hipMemsetAsync(cursor, 0, N_NODES * 4, stream);

    int eb = E_EDGES / 256;
    deg_kernel<<<eb, 256, 0, stream>>>(ew, src, deg);
    dis_kernel<<<N_NODES / 256, 256, 0, stream>>>(deg);
    count_kernel<<<eb, 256, 0, stream>>>(dst, cnt);
    scan_kernel<<<1, 256, 0, stream>>>(cnt, row_ptr);
    fill_csr<<<eb, 256, 0, stream>>>(src, dst, ew, deg, row_ptr, cursor, csr_src, csr_w);
    build_wcatT<<<(1024 * 1024) / 256, 256, 0, stream>>>(Ws, th, WT);
    build_bsum<<<4, 256, 0, stream>>>(bs, cbs, bsum);

    dim3 ggrid(N_NODES / GBM, ND / GBN);   // 64 x 8 = 512 blocks
    for (int t = 0; t < TSTEPS; t++) {
        u16* Hrd = (t & 1) ? Hb1 : Hb0;
        u16* Hwr = (t & 1) ? Hb0 : Hb1;
        // Tx1 = L_hat @ H   (+ fused X_t -> bf16 conversion)
        prop_kernel<<<N_NODES / 4, 256, 0, stream>>>(Hrd, nullptr, 1.f, row_ptr, csr_src,
                                                     csr_w, Tx1bf, X, t, Xtbf);
        // Tx2 = 2 * (L_hat @ Tx1) - H
        prop_kernel<<<N_NODES / 4, 256, 0, stream>>>(Tx1bf, Hrd, 2.f, row_ptr, csr_src,
                                                     csr_w, Tx2bf, nullptr, 0, nullptr);
        // gates + LSTM pointwise fused
        mfma_gemm<<<ggrid, 256, 0, stream>>>(Xtbf, Hrd, Tx1bf, Tx2bf, WT, bsum, C, H, Hwr,
                                             t == TSTEPS - 1 ? 1 : 0, t == 0 ? 1 : 0);
    }
}

// Round 10
// 1028.072 us; speedup vs baseline: 1.1559x; 1.1559x over previous
//
#include <hip/hip_runtime.h>
#include <cstddef>
#include <cstdint>

#define N_NODES 5120
#define E_EDGES 163840
#define F 256
#define TSTEPS 24
#define ND 1024          // GEMM N = 4*256 (gates, column-permuted)
#define XROWSTRIDE 6144  // T*F

typedef unsigned short u16;
typedef unsigned int u32;
typedef __bf16 bf16x8 __attribute__((ext_vector_type(8)));
typedef float f32x4 __attribute__((ext_vector_type(4)));

__device__ __forceinline__ u16 f2bf(float f) {
    u32 u = __float_as_uint(f);
    u = (u + 0x7FFFu + ((u >> 16) & 1u)) >> 16;  // round-to-nearest-even
    return (u16)u;
}
__device__ __forceinline__ float bf2f(u16 h) {
    return __uint_as_float((u32)h << 16);
}
__device__ __forceinline__ float fsigmoid(float x) {
    return 1.f / (1.f + __expf(-x));
}
__device__ __forceinline__ float ftanh(float x) {
    // tanh(x) = 1 - 2/(exp(2x)+1); saturates correctly for |x| large
    return 1.f - 2.f / (__expf(2.f * x) + 1.f);
}

// ---------------- graph preprocessing ----------------

__global__ void deg_kernel(const float* __restrict__ ew, const int* __restrict__ src,
                           float* __restrict__ deg) {
    int e = blockIdx.x * 256 + threadIdx.x;
    if (e < E_EDGES) atomicAdd(&deg[src[e]], ew[e]);
}

__global__ void dis_kernel(float* __restrict__ deg) {
    int n = blockIdx.x * 256 + threadIdx.x;
    if (n < N_NODES) {
        float d = deg[n];
        deg[n] = d > 0.f ? rsqrtf(d) : 0.f;
    }
}

__global__ void count_kernel(const int* __restrict__ dst, int* __restrict__ cnt) {
    int e = blockIdx.x * 256 + threadIdx.x;
    if (e < E_EDGES) atomicAdd(&cnt[dst[e]], 1);
}

// one block, 256 threads, 20 counts each (N_NODES = 256*20)
__global__ void scan_kernel(const int* __restrict__ cnt, int* __restrict__ row_ptr) {
    __shared__ int s[256];
    int tid = threadIdx.x;
    int base = tid * 20;
    int local[20];
    int sum = 0;
    #pragma unroll
    for (int i = 0; i < 20; i++) { local[i] = sum; sum += cnt[base + i]; }
    s[tid] = sum;
    __syncthreads();
    for (int off = 1; off < 256; off <<= 1) {
        int v = (tid >= off) ? s[tid - off] : 0;
        __syncthreads();
        s[tid] += v;
        __syncthreads();
    }
    int offset = (tid == 0) ? 0 : s[tid - 1];
    #pragma unroll
    for (int i = 0; i < 20; i++) row_ptr[base + i] = offset + local[i];
    if (tid == 0) row_ptr[N_NODES] = E_EDGES;
}

__global__ void fill_csr(const int* __restrict__ src, const int* __restrict__ dst,
                         const float* __restrict__ ew, const float* __restrict__ dis,
                         const int* __restrict__ row_ptr, int* __restrict__ cursor,
                         int* __restrict__ csr_src, float* __restrict__ csr_w) {
    int e = blockIdx.x * 256 + threadIdx.x;
    if (e >= E_EDGES) return;
    int s = src[e], d = dst[e];
    int pos = row_ptr[d] + atomicAdd(&cursor[d], 1);
    csr_src[pos] = s;
    // w_hat = (2/lambda_max)*(-dis[src]*w*dis[dst]); lambda_max=2 -> factor 1
    csr_w[pos] = -dis[s] * ew[e] * dis[d];
}

// Column permutation: col'(g, j) = (j>>4)*64 + g*16 + (j&15).
// Inverse: g = (c>>4)&3, j = (c>>6)*16 + (c&15).
// WT[c'][k] (bf16, k contiguous) = Wcat[k][g*256+j]
__global__ void build_wcatT(const float* __restrict__ Ws, const float* __restrict__ thetas,
                            u16* __restrict__ WT) {
    int idx = blockIdx.x * 256 + threadIdx.x;
    if (idx >= 1024 * 1024) return;
    int c = idx >> 10, k = idx & 1023;
    int g = (c >> 4) & 3;
    int j = (c >> 6) * 16 + (c & 15);
    float v;
    if (k < 256) {
        v = Ws[(g * 256 + k) * 256 + j];
    } else {
        int kc = (k >> 8) - 1;  // 0..2
        int rr = k & 255;
        v = thetas[((g * 3 + kc) * 256 + rr) * 256 + j];
    }
    WT[idx] = f2bf(v);
}

// bsum[c'] = bs[g*256+j] + cbs[g*256+j] in permuted column order
__global__ void build_bsum(const float* __restrict__ bs, const float* __restrict__ cbs,
                           float* __restrict__ bsum) {
    int c = blockIdx.x * 256 + threadIdx.x;
    if (c >= 1024) return;
    int g = (c >> 4) & 3;
    int j = (c >> 6) * 16 + (c & 15);
    bsum[c] = bs[g * 256 + j] + cbs[g * 256 + j];
}

// ---------------- prop: wave-per-node edge gather ----------------
// Node mapping XCD-aligned with gemm readers: block bid -> panel p = bid%80,
// sub i = bid/80, nodes n = p*64 + i*4 + wid. XCD(bid) = bid%8 = p%8 matches
// gemm A-panel reader XCD (gemm bid = x + 80y -> x%8). Writes land local-L2.

__global__ __launch_bounds__(256) void prop_kernel(
        const u16* __restrict__ xin, const u16* __restrict__ sub, float scale,
        const int* __restrict__ row_ptr, const int* __restrict__ csr_src,
        const float* __restrict__ csr_w, u16* __restrict__ out_bf,
        const float* __restrict__ X, int t, u16* __restrict__ xt_out) {
    __shared__ int s_src[4][64];
    __shared__ float s_w[4][64];
    int wid = threadIdx.x >> 6, l = threadIdx.x & 63;
    int p = blockIdx.x % 80, ii = blockIdx.x / 80;
    int n = p * 64 + ii * 4 + wid;
    int start = row_ptr[n], end = row_ptr[n + 1];
    float acc0 = 0.f, acc1 = 0.f, acc2 = 0.f, acc3 = 0.f;
    int fb = l * 4;  // this lane's 4 features
    for (int base = start; base < end; base += 64) {
        int chunk = min(64, end - base);
        if (l < chunk) {
            s_src[wid][l] = csr_src[base + l];
            s_w[wid][l] = csr_w[base + l];
        }
        #pragma unroll 4
        for (int i = 0; i < chunk; i++) {
            int s = s_src[wid][i];
            float wt = s_w[wid][i];
            ushort4 hv = *(const ushort4*)(xin + (size_t)s * F + fb);
            acc0 += wt * bf2f(hv.x);
            acc1 += wt * bf2f(hv.y);
            acc2 += wt * bf2f(hv.z);
            acc3 += wt * bf2f(hv.w);
        }
    }
    size_t o = (size_t)n * F + fb;
    float r0 = scale * acc0, r1 = scale * acc1, r2 = scale * acc2, r3 = scale * acc3;
    if (sub) {
        ushort4 sv = *(const ushort4*)(sub + o);
        r0 -= bf2f(sv.x); r1 -= bf2f(sv.y); r2 -= bf2f(sv.z); r3 -= bf2f(sv.w);
    }
    ushort4 ov;
    ov.x = f2bf(r0); ov.y = f2bf(r1); ov.z = f2bf(r2); ov.w = f2bf(r3);
    *(ushort4*)(out_bf + o) = ov;
    if (xt_out) {
        float4 xv = *(const float4*)(X + (size_t)n * XROWSTRIDE + (size_t)t * F + fb);
        ushort4 xo;
        xo.x = f2bf(xv.x); xo.y = f2bf(xv.y); xo.z = f2bf(xv.z); xo.w = f2bf(xv.w);
        *(ushort4*)(xt_out + o) = xo;
    }
}

// ---------------- fused bf16 MFMA GEMM + LSTM epilogue ----------------
// Tile 64x128, GBK=128 -> 8 K-steps (half the barrier/drain events of R4).
// Single-buffered LDS (R4-proven), grid 80x8 = 640 blocks. LDS 48 KB.
// A[5120,1024] = [Xt | Hb | Tx1 | Tx2] (bf16, row stride 256)
// WT = B^T in permuted column order (n-major, k-contig)
#define GBM 64
#define GBN 128
#define GBK 128

__global__ __launch_bounds__(256) void mfma_gemm(
        const u16* __restrict__ Xt, const u16* __restrict__ Hb,
        const u16* __restrict__ T1, const u16* __restrict__ T2,
        const u16* __restrict__ WT, const float* __restrict__ bsum,
        float* __restrict__ Cst, float* __restrict__ Hout, u16* __restrict__ HbNew,
        int writeH, int isFirst) {
    __shared__ alignas(16) u16 As[GBM * GBK];   // 16 KB, rows of 128
    __shared__ alignas(16) u16 Bs[GBN * GBK];   // 32 KB, rows of 128
    int tid = threadIdx.x;
    int w = tid >> 6, l = tid & 63;
    int m0 = blockIdx.x * GBM, n0 = blockIdx.y * GBN;
    int wm = (w >> 1) * 32, wn = (w & 1) * 64;   // wave sub-tile 32x64

    // staging: chunk c (1 KB) covers 4 rows of 128 elems; lane l -> row c*4 + l/16,
    // LDS col (l&15)*8. rule #21: linear LDS dest + inverse-swizzled SOURCE col
    // (scol = 8*((l&15) ^ (row&7)), row&7 = 4*(c&1) + l/16) + swizzled READ.
    int lrow = l >> 4;                 // 0..3
    int lcol16 = l & 15;

    f32x4 acc[2][4] = {};

    for (int k0 = 0; k0 < 1024; k0 += GBK) {
        int segi = k0 >> 8;
        const u16* ab = (segi == 0) ? Xt : (segi == 1) ? Hb : (segi == 2) ? T1 : T2;
        ab += (k0 & 255);
        const u16* bb = WT + k0;
        // A: 64 rows = 16 chunks (4 per wave)
        #pragma unroll
        for (int i = 0; i < 4; i++) {
            int c = i * 4 + w;
            int row = c * 4 + lrow;
            int scol = 8 * (lcol16 ^ (4 * (c & 1) + lrow));
            __builtin_amdgcn_global_load_lds(
                (const __attribute__((address_space(1))) u32*)(ab + (size_t)(m0 + row) * F + scol),
                (__attribute__((address_space(3))) u32*)(As + c * 512), 16, 0, 0);
        }
        // B: 128 rows = 32 chunks (8 per wave)
        #pragma unroll
        for (int i = 0; i < 8; i++) {
            int c = i * 4 + w;
            int row = c * 4 + lrow;
            int scol = 8 * (lcol16 ^ (4 * (c & 1) + lrow));
            __builtin_amdgcn_global_load_lds(
                (const __attribute__((address_space(1))) u32*)(bb + (size_t)(n0 + row) * 1024 + scol),
                (__attribute__((address_space(3))) u32*)(Bs + c * 512), 16, 0, 0);
        }
        __syncthreads();
        #pragma unroll
        for (int kk = 0; kk < 4; kk++) {
            int kr = kk * 32 + (l >> 4) * 8;
            bf16x8 af[2], bfr[4];
            #pragma unroll
            for (int mf = 0; mf < 2; mf++) {
                int r = wm + mf * 16 + (l & 15);
                af[mf] = *(const bf16x8*)(As + r * GBK + (kr ^ ((r & 7) << 3)));
            }
            #pragma unroll
            for (int nf = 0; nf < 4; nf++) {
                int r = wn + nf * 16 + (l & 15);
                bfr[nf] = *(const bf16x8*)(Bs + r * GBK + (kr ^ ((r & 7) << 3)));
            }
            #pragma unroll
            for (int mf = 0; mf < 2; mf++)
                #pragma unroll
                for (int nf = 0; nf < 4; nf++)
                    acc[mf][nf] = __builtin_amdgcn_mfma_f32_16x16x32_bf16(
                        af[mf], bfr[nf], acc[mf][nf], 0, 0, 0);
        }
        __syncthreads();
    }

    // LSTM epilogue. C/D layout: col = lane&15, row = (lane>>4)*4 + reg.
    // nf = gate (I,F,T,O); feature j = group*16 + cc, group = n0/64 + (w&1).
    int cr = (l >> 4) * 4, cc = l & 15;
    int feat = ((n0 >> 6) + (w & 1)) * 16 + cc;
    float bI = bsum[n0 + wn + 0  + cc];
    float bF = bsum[n0 + wn + 16 + cc];
    float bT = bsum[n0 + wn + 32 + cc];
    float bO = bsum[n0 + wn + 48 + cc];
    #pragma unroll
    for (int mf = 0; mf < 2; mf++) {
        #pragma unroll
        for (int r = 0; r < 4; r++) {
            int row = m0 + wm + mf * 16 + cr + r;
            size_t o = (size_t)row * F + feat;
            float I  = fsigmoid(acc[mf][0][r] + bI);
            float Fg = fsigmoid(acc[mf][1][r] + bF);
            float Tc = ftanh(acc[mf][2][r] + bT);
            float O  = fsigmoid(acc[mf][3][r] + bO);
            float cprev = isFirst ? 0.f : Cst[o];   // t=0: C starts at zero (buffer poisoned)
            float c  = Fg * cprev + I * Tc;
            Cst[o] = c;
            float h = O * ftanh(c);
            if (writeH) Hout[o] = h;   // fp32 H only needed at the final step
            HbNew[o] = f2bf(h);
        }
    }
}

// ---------------- launch ----------------

extern "C" void kernel_launch(void* const* d_in, const int* in_sizes, int n_in,
                              void* d_out, int out_size, void* d_ws, size_t ws_size,
                              hipStream_t stream) {
    const float* X   = (const float*)d_in[0];
    const float* ew  = (const float*)d_in[1];
    const float* Ws  = (const float*)d_in[2];
    const float* bs  = (const float*)d_in[3];
    const float* th  = (const float*)d_in[4];
    const float* cbs = (const float*)d_in[5];
    const int*   ei  = (const int*)d_in[6];
    const int* src = ei;
    const int* dst = ei + E_EDGES;

    float* H = (float*)d_out;               // N*F
    float* C = H + (size_t)N_NODES * F;     // N*F

    char* w = (char*)d_ws;
    size_t off = 0;
    auto alloc = [&](size_t bytes) {
        void* p = w + off;
        off += (bytes + 255) & ~(size_t)255;
        return p;
    };
    float* deg     = (float*)alloc(N_NODES * 4);
    int*   cnt     = (int*)  alloc(N_NODES * 4);
    int*   cursor  = (int*)  alloc(N_NODES * 4);
    int*   row_ptr = (int*)  alloc((N_NODES + 1) * 4);
    int*   csr_src = (int*)  alloc(E_EDGES * 4);
    float* csr_w   = (float*)alloc(E_EDGES * 4);
    u16*   WT      = (u16*)  alloc((size_t)1024 * 1024 * 2);
    float* bsum    = (float*)alloc(1024 * 4);
    u16*   Xtbf    = (u16*)  alloc((size_t)N_NODES * F * 2);
    u16*   Hb0     = (u16*)  alloc((size_t)N_NODES * F * 2);
    u16*   Hb1     = (u16*)  alloc((size_t)N_NODES * F * 2);
    u16*   Tx1bf   = (u16*)  alloc((size_t)N_NODES * F * 2);
    u16*   Tx2bf   = (u16*)  alloc((size_t)N_NODES * F * 2);

    hipMemsetAsync(Hb0, 0, (size_t)N_NODES * F * 2, stream);
    hipMemsetAsync(deg, 0, N_NODES * 4, stream);
    hipMemsetAsync(cnt, 0, N_NODES * 4, stream);
    hipMemsetAsync(cursor, 0, N_NODES * 4, stream);

    int eb = E_EDGES / 256;
    deg_kernel<<<eb, 256, 0, stream>>>(ew, src, deg);
    dis_kernel<<<N_NODES / 256, 256, 0, stream>>>(deg);
    count_kernel<<<eb, 256, 0, stream>>>(dst, cnt);
    scan_kernel<<<1, 256, 0, stream>>>(cnt, row_ptr);
    fill_csr<<<eb, 256, 0, stream>>>(src, dst, ew, deg, row_ptr, cursor, csr_src, csr_w);
    build_wcatT<<<(1024 * 1024) / 256, 256, 0, stream>>>(Ws, th, WT);
    build_bsum<<<4, 256, 0, stream>>>(bs, cbs, bsum);

    dim3 ggrid(N_NODES / GBM, ND / GBN);   // 80 x 8 = 640 blocks
    for (int t = 0; t < TSTEPS; t++) {
        u16* Hrd = (t & 1) ? Hb1 : Hb0;
        u16* Hwr = (t & 1) ? Hb0 : Hb1;
        // Tx1 = L_hat @ H   (+ fused X_t -> bf16 conversion)
        prop_kernel<<<N_NODES / 4, 256, 0, stream>>>(Hrd, nullptr, 1.f, row_ptr, csr_src,
                                                     csr_w, Tx1bf, X, t, Xtbf);
        // Tx2 = 2 * (L_hat @ Tx1) - H
        prop_kernel<<<N_NODES / 4, 256, 0, stream>>>(Tx1bf, Hrd, 2.f, row_ptr, csr_src,
                                                     csr_w, Tx2bf, nullptr, 0, nullptr);
        // gates + LSTM pointwise fused
        mfma_gemm<<<ggrid, 256, 0, stream>>>(Xtbf, Hrd, Tx1bf, Tx2bf, WT, bsum, C, H, Hwr,
                                             t == TSTEPS - 1 ? 1 : 0, t == 0 ? 1 : 0);
    }
}